// Round 1
// baseline (524.757 us; speedup 1.0000x reference)
//
#include <hip/hip_runtime.h>

#define T_TOK 4096
#define DIN   1024
#define DOUT  1024
#define NEXP  8
#define HDIM  4096
#define RCAP  9216
#define MAXTILE 72

typedef float f32x4 __attribute__((ext_vector_type(4)));
typedef short bf16x8 __attribute__((ext_vector_type(8)));
typedef unsigned short u16x4 __attribute__((ext_vector_type(4)));

__device__ __forceinline__ float bf2f(unsigned short u) {
    union { unsigned int i; float f; } v; v.i = ((unsigned int)u) << 16; return v.f;
}
__device__ __forceinline__ unsigned short f2bf(float f) {
    union { unsigned int i; float f; } v; v.f = f;
    unsigned int r = v.i + 0x7FFFu + ((v.i >> 16) & 1u);
    return (unsigned short)(r >> 16);
}

__global__ void init_kernel(int* cnt) {
    if (threadIdx.x < NEXP) cnt[threadIdx.x] = 0;
}

// One wave per token: fp64 gating dots, softplus, top-2, softmax, routing.
__global__ __launch_bounds__(64) void gating_kernel(
    const float* __restrict__ x, const float* __restrict__ noise,
    const float* __restrict__ gw, const float* __restrict__ gb,
    const float* __restrict__ nw, const float* __restrict__ nb,
    float* __restrict__ wout, int* __restrict__ cnt,
    int* __restrict__ tok_e, int* __restrict__ tok_slot, float* __restrict__ tok_p)
{
    int t = blockIdx.x;
    int lane = threadIdx.x;
    const float* xr = x + (size_t)t * DIN;
    double ag[NEXP], an[NEXP];
#pragma unroll
    for (int e = 0; e < NEXP; ++e) { ag[e] = 0.0; an[e] = 0.0; }
    for (int d = lane; d < DIN; d += 64) {
        double xv = (double)xr[d];
        const f32x4* g4 = (const f32x4*)(gw + (size_t)d * NEXP);
        const f32x4* n4 = (const f32x4*)(nw + (size_t)d * NEXP);
        f32x4 ga = g4[0], gbv = g4[1], na = n4[0], nbv = n4[1];
#pragma unroll
        for (int j = 0; j < 4; ++j) {
            ag[j]     += xv * (double)ga[j];
            ag[4 + j] += xv * (double)gbv[j];
            an[j]     += xv * (double)na[j];
            an[4 + j] += xv * (double)nbv[j];
        }
    }
#pragma unroll
    for (int e = 0; e < NEXP; ++e) {
        double g = ag[e], n = an[e];
#pragma unroll
        for (int m = 32; m > 0; m >>= 1) { g += __shfl_xor(g, m); n += __shfl_xor(n, m); }
        ag[e] = g; an[e] = n;
    }
    double lg[NEXP];
#pragma unroll
    for (int e = 0; e < NEXP; ++e) {
        double z = an[e] + (double)nb[e];
        double sp = fmax(z, 0.0) + log1p(exp(-fabs(z)));   // softplus = logaddexp(z, 0)
        lg[e] = ag[e] + (double)gb[e] + (double)noise[(size_t)t * NEXP + e] * sp;
    }
    int i0 = 0; double v0 = lg[0];
#pragma unroll
    for (int e = 1; e < NEXP; ++e) if (lg[e] > v0) { v0 = lg[e]; i0 = e; }
    int i1 = -1; double v1 = -1.0e300;
#pragma unroll
    for (int e = 0; e < NEXP; ++e) if (e != i0 && lg[e] > v1) { v1 = lg[e]; i1 = e; }
    double d1 = exp(v1 - v0);
    float p0 = (float)(1.0 / (1.0 + d1));
    float p1 = (float)(d1 / (1.0 + d1));
    if (lane < NEXP) {
        float wv = (lane == i0) ? p0 : ((lane == i1) ? p1 : 0.0f);
        wout[(size_t)t * NEXP + lane] = wv;
    }
    if (lane == 0) {
        int s0 = atomicAdd(&cnt[i0], 1);
        int s1 = atomicAdd(&cnt[i1], 1);
        tok_e[2 * t] = i0;     tok_e[2 * t + 1] = i1;
        tok_slot[2 * t] = s0;  tok_slot[2 * t + 1] = s1;
        tok_p[2 * t] = p0;     tok_p[2 * t + 1] = p1;
    }
}

// 128-row-aligned per-expert offsets + row-tile -> expert map (<= 72 tiles).
__global__ void prefix_kernel(const int* __restrict__ cnt, int* __restrict__ poff,
                              int* __restrict__ t2e, int* __restrict__ trow)
{
    if (threadIdx.x != 0 || blockIdx.x != 0) return;
    int base = 0, tid = 0;
    for (int e = 0; e < NEXP; ++e) {
        poff[e] = base;
        int c = cnt[e];
        int nt = (c + 127) >> 7;
        for (int i = 0; i < nt; ++i) { t2e[tid] = e; trow[tid] = base + (i << 7); ++tid; }
        base += nt << 7;
    }
    for (; tid < MAXTILE; ++tid) { t2e[tid] = -1; trow[tid] = 0; }
}

// Copy token row t (fp32) to its expert slot as bf16.
__global__ __launch_bounds__(256) void gather_kernel(
    const float* __restrict__ x, const int* __restrict__ tok_e,
    const int* __restrict__ tok_slot, const int* __restrict__ poff,
    unsigned short* __restrict__ Xg)
{
    int b = blockIdx.x;
    int t = b >> 1, k = b & 1;
    int e = tok_e[2 * t + k];
    int row = poff[e] + tok_slot[2 * t + k];
    int c = threadIdx.x << 2;
    f32x4 v = *(const f32x4*)(x + (size_t)t * DIN + c);
    u16x4 o;
#pragma unroll
    for (int j = 0; j < 4; ++j) o[j] = f2bf(v[j]);
    *(u16x4*)(Xg + (size_t)row * DIN + c) = o;
}

// Transpose+convert: W [E][K][N] fp32 -> Wt [E][N][K] bf16 (64x64 LDS tiles).
__global__ __launch_bounds__(256) void convw_kernel(
    const float* __restrict__ W, unsigned short* __restrict__ Wt, int K, int N)
{
    __shared__ float tile[64][65];
    int e = blockIdx.x;
    int k0 = blockIdx.y << 6;
    int n0 = blockIdx.z << 6;
    const float* src = W + ((size_t)e * K + k0) * N + n0;
#pragma unroll
    for (int i = 0; i < 16; ++i) {
        int lin = threadIdx.x + (i << 8);
        int r = lin >> 6, c = lin & 63;
        tile[r][c] = src[(size_t)r * N + c];
    }
    __syncthreads();
    unsigned short* dst = Wt + ((size_t)e * N + n0) * K + k0;
#pragma unroll
    for (int i = 0; i < 16; ++i) {
        int lin = threadIdx.x + (i << 8);
        int n = lin >> 6, kk = lin & 63;
        dst[(size_t)n * K + kk] = f2bf(tile[kk][n]);
    }
}

// 128x128 tile, BK=32, 4 waves each 64x64, global_load_lds staging,
// mfma_f32_16x16x32_bf16, bias (+ReLU) epilogue, bf16 C.
__global__ __launch_bounds__(256, 2) void gemm_bt_kernel(
    const unsigned short* __restrict__ A,   // [rows][K] bf16
    const unsigned short* __restrict__ Bt,  // [E][N][K] bf16
    unsigned short* __restrict__ C,         // [rows][N] bf16
    const float* __restrict__ bias,         // [E][N]
    const int* __restrict__ t2e, const int* __restrict__ trow,
    int K, int N, int relu)
{
    int e = t2e[blockIdx.x];
    if (e < 0) return;
    int row0 = trow[blockIdx.x];
    int n0 = blockIdx.y << 7;

    __shared__ __align__(16) unsigned short As[128 * 32];
    __shared__ __align__(16) unsigned short Bs[128 * 32];

    int tid = threadIdx.x;
    int lane = tid & 63;
    int wv = tid >> 6;
    int wr = (wv >> 1) << 6;
    int wc = (wv & 1) << 6;

    const unsigned short* Ab = A + (size_t)row0 * K;
    const unsigned short* Bb = Bt + ((size_t)e * N + n0) * K;

    f32x4 acc[4][4] = {};

    int hr = lane & 15;
    int kq = (lane >> 4) << 3;
    int srow = lane >> 2;
    int skc = (lane & 3) << 3;

    int nkt = K >> 5;
    for (int kt = 0; kt < nkt; ++kt) {
        __syncthreads();
        int kb = kt << 5;
#pragma unroll
        for (int j = 0; j < 2; ++j) {
            int c = wv + (j << 2);           // chunk 0..7 (1 KiB each)
            int r = (c << 4) + srow;         // tile row 0..127
            const unsigned short* ga = Ab + (size_t)r * K + kb + skc;
            const unsigned short* gbp = Bb + (size_t)r * K + kb + skc;
            __builtin_amdgcn_global_load_lds(
                (const __attribute__((address_space(1))) void*)ga,
                (__attribute__((address_space(3))) void*)(&As[c << 9]), 16, 0, 0);
            __builtin_amdgcn_global_load_lds(
                (const __attribute__((address_space(1))) void*)gbp,
                (__attribute__((address_space(3))) void*)(&Bs[c << 9]), 16, 0, 0);
        }
        __syncthreads();
        bf16x8 af[4], bfv[4];
#pragma unroll
        for (int m = 0; m < 4; ++m)
            af[m] = *(const bf16x8*)(&As[((wr + (m << 4) + hr) << 5) + kq]);
#pragma unroll
        for (int n = 0; n < 4; ++n)
            bfv[n] = *(const bf16x8*)(&Bs[((wc + (n << 4) + hr) << 5) + kq]);
#pragma unroll
        for (int m = 0; m < 4; ++m)
#pragma unroll
            for (int n = 0; n < 4; ++n)
                acc[m][n] = __builtin_amdgcn_mfma_f32_16x16x32_bf16(af[m], bfv[n], acc[m][n], 0, 0, 0);
    }

    int rq = (lane >> 4) << 2;
    int cl = lane & 15;
#pragma unroll
    for (int n = 0; n < 4; ++n) {
        int col = wc + (n << 4) + cl;
        float bv = bias[(size_t)e * N + n0 + col];
#pragma unroll
        for (int m = 0; m < 4; ++m) {
#pragma unroll
            for (int r = 0; r < 4; ++r) {
                int row = wr + (m << 4) + rq + r;
                float v = acc[m][n][r] + bv;
                if (relu) v = fmaxf(v, 0.0f);
                C[(size_t)(row0 + row) * N + n0 + col] = f2bf(v);
            }
        }
    }
}

// x_out[t] = p0*O[row0] + p1*O[row1]
__global__ __launch_bounds__(256) void combine_kernel(
    const unsigned short* __restrict__ O, const int* __restrict__ tok_e,
    const int* __restrict__ tok_slot, const float* __restrict__ tok_p,
    const int* __restrict__ poff, float* __restrict__ xout)
{
    int t = blockIdx.x;
    int e0 = tok_e[2 * t], e1 = tok_e[2 * t + 1];
    int r0 = poff[e0] + tok_slot[2 * t];
    int r1 = poff[e1] + tok_slot[2 * t + 1];
    float p0 = tok_p[2 * t], p1 = tok_p[2 * t + 1];
    int c = threadIdx.x << 2;
    u16x4 a = *(const u16x4*)(O + (size_t)r0 * DOUT + c);
    u16x4 b = *(const u16x4*)(O + (size_t)r1 * DOUT + c);
    f32x4 r;
#pragma unroll
    for (int j = 0; j < 4; ++j) r[j] = p0 * bf2f(a[j]) + p1 * bf2f(b[j]);
    *(f32x4*)(xout + (size_t)t * DOUT + c) = r;
}

extern "C" void kernel_launch(void* const* d_in, const int* in_sizes, int n_in,
                              void* d_out, int out_size, void* d_ws, size_t ws_size,
                              hipStream_t stream)
{
    const float* x     = (const float*)d_in[0];
    const float* noise = (const float*)d_in[1];
    const float* gw    = (const float*)d_in[2];
    const float* gb    = (const float*)d_in[3];
    const float* nw    = (const float*)d_in[4];
    const float* nb    = (const float*)d_in[5];
    const float* w1    = (const float*)d_in[6];
    const float* b1    = (const float*)d_in[7];
    const float* w2    = (const float*)d_in[8];
    const float* b2    = (const float*)d_in[9];
    float* xout = (float*)d_out;
    float* wout = xout + (size_t)T_TOK * DOUT;

    char* ws = (char*)d_ws;
    int*   cnt      = (int*)(ws + 0);
    int*   poff     = (int*)(ws + 256);
    int*   t2e      = (int*)(ws + 512);
    int*   trow     = (int*)(ws + 1024);
    int*   tok_e    = (int*)(ws + 2048);
    int*   tok_slot = (int*)(ws + 2048 + 4 * 2 * T_TOK);
    float* tok_p    = (float*)(ws + 2048 + 8 * 2 * T_TOK);
    size_t oXg = 2048 + 12 * 2 * T_TOK;                 // = 100352, 256-aligned
    unsigned short* Xg  = (unsigned short*)(ws + oXg);
    size_t oH  = oXg + (size_t)RCAP * DIN * 2;
    unsigned short* H   = (unsigned short*)(ws + oH);
    size_t oO  = oH + (size_t)RCAP * HDIM * 2;
    unsigned short* O   = (unsigned short*)(ws + oO);
    size_t oW1 = oO + (size_t)RCAP * DOUT * 2;
    unsigned short* W1t = (unsigned short*)(ws + oW1);
    size_t oW2 = oW1 + (size_t)NEXP * HDIM * DIN * 2;
    unsigned short* W2t = (unsigned short*)(ws + oW2);
    // total ~247.6 MB

    init_kernel<<<1, 64, 0, stream>>>(cnt);
    gating_kernel<<<T_TOK, 64, 0, stream>>>(x, noise, gw, gb, nw, nb,
                                            wout, cnt, tok_e, tok_slot, tok_p);
    prefix_kernel<<<1, 1, 0, stream>>>(cnt, poff, t2e, trow);
    gather_kernel<<<2 * T_TOK, 256, 0, stream>>>(x, tok_e, tok_slot, poff, Xg);
    convw_kernel<<<dim3(NEXP, DIN / 64, HDIM / 64), 256, 0, stream>>>(w1, W1t, DIN, HDIM);
    convw_kernel<<<dim3(NEXP, HDIM / 64, DOUT / 64), 256, 0, stream>>>(w2, W2t, HDIM, DOUT);
    gemm_bt_kernel<<<dim3(MAXTILE, HDIM / 128), 256, 0, stream>>>(
        Xg, W1t, H, b1, t2e, trow, DIN, HDIM, 1);
    gemm_bt_kernel<<<dim3(MAXTILE, DOUT / 128), 256, 0, stream>>>(
        H, W2t, O, b2, t2e, trow, HDIM, DOUT, 0);
    combine_kernel<<<T_TOK, 256, 0, stream>>>(O, tok_e, tok_slot, tok_p, poff, xout);
}

// Round 2
// 448.752 us; speedup vs baseline: 1.1694x; 1.1694x over previous
//
#include <hip/hip_runtime.h>

#define T_TOK 4096
#define DIN   1024
#define DOUT  1024
#define NEXP  8
#define HDIM  4096
#define RCAP  9216
#define MAXTILE 72

typedef float f32x4 __attribute__((ext_vector_type(4)));
typedef short bf16x8 __attribute__((ext_vector_type(8)));
typedef unsigned short u16x4 __attribute__((ext_vector_type(4)));

__device__ __forceinline__ float bf2f(unsigned short u) {
    union { unsigned int i; float f; } v; v.i = ((unsigned int)u) << 16; return v.f;
}
__device__ __forceinline__ unsigned short f2bf(float f) {
    union { unsigned int i; float f; } v; v.f = f;
    unsigned int r = v.i + 0x7FFFu + ((v.i >> 16) & 1u);
    return (unsigned short)(r >> 16);
}

__global__ void init_kernel(int* cnt) {
    if (threadIdx.x < NEXP) cnt[threadIdx.x] = 0;
}

// One wave per token: fp64 gating dots, softplus, top-2, softmax, routing.
__global__ __launch_bounds__(64) void gating_kernel(
    const float* __restrict__ x, const float* __restrict__ noise,
    const float* __restrict__ gw, const float* __restrict__ gb,
    const float* __restrict__ nw, const float* __restrict__ nb,
    float* __restrict__ wout, int* __restrict__ cnt,
    int* __restrict__ tok_e, int* __restrict__ tok_slot, float* __restrict__ tok_p)
{
    int t = blockIdx.x;
    int lane = threadIdx.x;
    const float* xr = x + (size_t)t * DIN;
    double ag[NEXP], an[NEXP];
#pragma unroll
    for (int e = 0; e < NEXP; ++e) { ag[e] = 0.0; an[e] = 0.0; }
    for (int d = lane; d < DIN; d += 64) {
        double xv = (double)xr[d];
        const f32x4* g4 = (const f32x4*)(gw + (size_t)d * NEXP);
        const f32x4* n4 = (const f32x4*)(nw + (size_t)d * NEXP);
        f32x4 ga = g4[0], gbv = g4[1], na = n4[0], nbv = n4[1];
#pragma unroll
        for (int j = 0; j < 4; ++j) {
            ag[j]     += xv * (double)ga[j];
            ag[4 + j] += xv * (double)gbv[j];
            an[j]     += xv * (double)na[j];
            an[4 + j] += xv * (double)nbv[j];
        }
    }
#pragma unroll
    for (int e = 0; e < NEXP; ++e) {
        double g = ag[e], n = an[e];
#pragma unroll
        for (int m = 32; m > 0; m >>= 1) { g += __shfl_xor(g, m); n += __shfl_xor(n, m); }
        ag[e] = g; an[e] = n;
    }
    double lg[NEXP];
#pragma unroll
    for (int e = 0; e < NEXP; ++e) {
        double z = an[e] + (double)nb[e];
        double sp = fmax(z, 0.0) + log1p(exp(-fabs(z)));   // softplus = logaddexp(z, 0)
        lg[e] = ag[e] + (double)gb[e] + (double)noise[(size_t)t * NEXP + e] * sp;
    }
    int i0 = 0; double v0 = lg[0];
#pragma unroll
    for (int e = 1; e < NEXP; ++e) if (lg[e] > v0) { v0 = lg[e]; i0 = e; }
    int i1 = -1; double v1 = -1.0e300;
#pragma unroll
    for (int e = 0; e < NEXP; ++e) if (e != i0 && lg[e] > v1) { v1 = lg[e]; i1 = e; }
    double d1 = exp(v1 - v0);
    float p0 = (float)(1.0 / (1.0 + d1));
    float p1 = (float)(d1 / (1.0 + d1));
    if (lane < NEXP) {
        float wv = (lane == i0) ? p0 : ((lane == i1) ? p1 : 0.0f);
        wout[(size_t)t * NEXP + lane] = wv;
    }
    if (lane == 0) {
        int s0 = atomicAdd(&cnt[i0], 1);
        int s1 = atomicAdd(&cnt[i1], 1);
        tok_e[2 * t] = i0;     tok_e[2 * t + 1] = i1;
        tok_slot[2 * t] = s0;  tok_slot[2 * t + 1] = s1;
        tok_p[2 * t] = p0;     tok_p[2 * t + 1] = p1;
    }
}

// 128-row-aligned per-expert offsets + row-tile -> expert map (<= 72 tiles).
__global__ void prefix_kernel(const int* __restrict__ cnt, int* __restrict__ poff,
                              int* __restrict__ t2e, int* __restrict__ trow)
{
    if (threadIdx.x != 0 || blockIdx.x != 0) return;
    int base = 0, tid = 0;
    for (int e = 0; e < NEXP; ++e) {
        poff[e] = base;
        int c = cnt[e];
        int nt = (c + 127) >> 7;
        for (int i = 0; i < nt; ++i) { t2e[tid] = e; trow[tid] = base + (i << 7); ++tid; }
        base += nt << 7;
    }
    for (; tid < MAXTILE; ++tid) { t2e[tid] = -1; trow[tid] = 0; }
}

// Copy token row t (fp32) to its expert slot as bf16.
__global__ __launch_bounds__(256) void gather_kernel(
    const float* __restrict__ x, const int* __restrict__ tok_e,
    const int* __restrict__ tok_slot, const int* __restrict__ poff,
    unsigned short* __restrict__ Xg)
{
    int b = blockIdx.x;
    int t = b >> 1, k = b & 1;
    int e = tok_e[2 * t + k];
    int row = poff[e] + tok_slot[2 * t + k];
    int c = threadIdx.x << 2;
    f32x4 v = *(const f32x4*)(x + (size_t)t * DIN + c);
    u16x4 o;
#pragma unroll
    for (int j = 0; j < 4; ++j) o[j] = f2bf(v[j]);
    *(u16x4*)(Xg + (size_t)row * DIN + c) = o;
}

// Transpose+convert: W [E][K][N] fp32 -> Wt [E][N][K] bf16 (64x64 LDS tiles).
// float4 loads, u16x4 stores.
__global__ __launch_bounds__(256) void convw_kernel(
    const float* __restrict__ W, unsigned short* __restrict__ Wt, int K, int N)
{
    __shared__ float tile[64][65];
    int e = blockIdx.x;
    int k0 = blockIdx.y << 6;
    int n0 = blockIdx.z << 6;
    int tid = threadIdx.x;
    const float* src = W + ((size_t)e * K + k0) * N + n0;
    int r = tid >> 4, c4 = (tid & 15) << 2;
#pragma unroll
    for (int i = 0; i < 4; ++i) {
        f32x4 v = *(const f32x4*)(src + (size_t)(r + (i << 4)) * N + c4);
        *(f32x4*)(&tile[r + (i << 4)][c4]) = v;
    }
    __syncthreads();
    unsigned short* dst = Wt + ((size_t)e * N + n0) * K + k0;
    int n = tid >> 2, kq = (tid & 3) << 4;
#pragma unroll
    for (int j = 0; j < 4; ++j) {
        int kk = kq + (j << 2);
        u16x4 o;
#pragma unroll
        for (int q = 0; q < 4; ++q) o[q] = f2bf(tile[kk + q][n]);
        *(u16x4*)(dst + (size_t)n * K + kk) = o;
    }
}

// 128x128 tile, BK=32, 4 waves each 64x64, global_load_lds staging with
// both-sides slot swizzle (slot ^= (row>>1)&3), XCD-chunked n-fastest block
// order, mfma_f32_16x16x32_bf16, bias (+ReLU) epilogue, bf16 C.
__global__ __launch_bounds__(256, 2) void gemm_bt_kernel(
    const unsigned short* __restrict__ A,   // [rows][K] bf16
    const unsigned short* __restrict__ Bt,  // [E][N][K] bf16
    unsigned short* __restrict__ C,         // [rows][N] bf16
    const float* __restrict__ bias,         // [E][N]
    const int* __restrict__ t2e, const int* __restrict__ trow,
    int K, int N, int nbshift, int relu)
{
    // XCD-chunked bijective remap (nwg % 8 == 0), n-block fastest within chunk.
    int nwg = gridDim.x;
    int cpx = nwg >> 3;
    int wg = ((blockIdx.x & 7) * cpx) + (blockIdx.x >> 3);
    int tileid = wg >> nbshift;
    int nb = wg & ((1 << nbshift) - 1);

    int e = t2e[tileid];
    if (e < 0) return;
    int row0 = trow[tileid];
    int n0 = nb << 7;

    __shared__ __align__(16) unsigned short As[128 * 32];
    __shared__ __align__(16) unsigned short Bs[128 * 32];

    int tid = threadIdx.x;
    int lane = tid & 63;
    int wv = tid >> 6;
    int wr = (wv >> 1) << 6;
    int wc = (wv & 1) << 6;

    const unsigned short* Ab = A + (size_t)row0 * K;
    const unsigned short* Bb = Bt + ((size_t)e * N + n0) * K;

    f32x4 acc[4][4] = {};

    // staging: LDS linear dest (c*1024 + lane*16); source slot pre-swizzled
    int srow = lane >> 2;                       // row within 16-row chunk
    int skc = (((lane & 3) ^ ((lane >> 3) & 3)) << 3);  // swizzled k-slot * 8 elems
    // fragment read: same involution on the read side
    int hr = lane & 15;
    int rsw = (lane >> 1) & 3;                  // == (row>>1)&3 for this lane's rows
    int kfrag = (((lane >> 4) ^ rsw) << 3);     // swizzled element offset

    int nkt = K >> 5;
    for (int kt = 0; kt < nkt; ++kt) {
        __syncthreads();
        int kb = kt << 5;
#pragma unroll
        for (int j = 0; j < 2; ++j) {
            int c = wv + (j << 2);           // chunk 0..7 (1 KiB each)
            int r = (c << 4) + srow;         // tile row 0..127
            const unsigned short* ga = Ab + (size_t)r * K + kb + skc;
            const unsigned short* gbp = Bb + (size_t)r * K + kb + skc;
            __builtin_amdgcn_global_load_lds(
                (const __attribute__((address_space(1))) void*)ga,
                (__attribute__((address_space(3))) void*)(&As[c << 9]), 16, 0, 0);
            __builtin_amdgcn_global_load_lds(
                (const __attribute__((address_space(1))) void*)gbp,
                (__attribute__((address_space(3))) void*)(&Bs[c << 9]), 16, 0, 0);
        }
        __syncthreads();
        bf16x8 af[4], bfv[4];
#pragma unroll
        for (int m = 0; m < 4; ++m)
            af[m] = *(const bf16x8*)(&As[((wr + (m << 4) + hr) << 5) + kfrag]);
#pragma unroll
        for (int n = 0; n < 4; ++n)
            bfv[n] = *(const bf16x8*)(&Bs[((wc + (n << 4) + hr) << 5) + kfrag]);
#pragma unroll
        for (int m = 0; m < 4; ++m)
#pragma unroll
            for (int n = 0; n < 4; ++n)
                acc[m][n] = __builtin_amdgcn_mfma_f32_16x16x32_bf16(af[m], bfv[n], acc[m][n], 0, 0, 0);
    }

    int rq = (lane >> 4) << 2;
    int cl = lane & 15;
#pragma unroll
    for (int n = 0; n < 4; ++n) {
        int col = wc + (n << 4) + cl;
        float bv = bias[(size_t)e * N + n0 + col];
#pragma unroll
        for (int m = 0; m < 4; ++m) {
#pragma unroll
            for (int r = 0; r < 4; ++r) {
                int row = wr + (m << 4) + rq + r;
                float v = acc[m][n][r] + bv;
                if (relu) v = fmaxf(v, 0.0f);
                C[(size_t)(row0 + row) * N + n0 + col] = f2bf(v);
            }
        }
    }
}

// x_out[t] = p0*O[row0] + p1*O[row1]
__global__ __launch_bounds__(256) void combine_kernel(
    const unsigned short* __restrict__ O, const int* __restrict__ tok_e,
    const int* __restrict__ tok_slot, const float* __restrict__ tok_p,
    const int* __restrict__ poff, float* __restrict__ xout)
{
    int t = blockIdx.x;
    int e0 = tok_e[2 * t], e1 = tok_e[2 * t + 1];
    int r0 = poff[e0] + tok_slot[2 * t];
    int r1 = poff[e1] + tok_slot[2 * t + 1];
    float p0 = tok_p[2 * t], p1 = tok_p[2 * t + 1];
    int c = threadIdx.x << 2;
    u16x4 a = *(const u16x4*)(O + (size_t)r0 * DOUT + c);
    u16x4 b = *(const u16x4*)(O + (size_t)r1 * DOUT + c);
    f32x4 r;
#pragma unroll
    for (int j = 0; j < 4; ++j) r[j] = p0 * bf2f(a[j]) + p1 * bf2f(b[j]);
    *(f32x4*)(xout + (size_t)t * DOUT + c) = r;
}

extern "C" void kernel_launch(void* const* d_in, const int* in_sizes, int n_in,
                              void* d_out, int out_size, void* d_ws, size_t ws_size,
                              hipStream_t stream)
{
    const float* x     = (const float*)d_in[0];
    const float* noise = (const float*)d_in[1];
    const float* gw    = (const float*)d_in[2];
    const float* gb    = (const float*)d_in[3];
    const float* nw    = (const float*)d_in[4];
    const float* nb    = (const float*)d_in[5];
    const float* w1    = (const float*)d_in[6];
    const float* b1    = (const float*)d_in[7];
    const float* w2    = (const float*)d_in[8];
    const float* b2    = (const float*)d_in[9];
    float* xout = (float*)d_out;
    float* wout = xout + (size_t)T_TOK * DOUT;

    char* ws = (char*)d_ws;
    int*   cnt      = (int*)(ws + 0);
    int*   poff     = (int*)(ws + 256);
    int*   t2e      = (int*)(ws + 512);
    int*   trow     = (int*)(ws + 1024);
    int*   tok_e    = (int*)(ws + 2048);
    int*   tok_slot = (int*)(ws + 2048 + 4 * 2 * T_TOK);
    float* tok_p    = (float*)(ws + 2048 + 8 * 2 * T_TOK);
    size_t oXg = 2048 + 12 * 2 * T_TOK;                 // = 100352, 256-aligned
    unsigned short* Xg  = (unsigned short*)(ws + oXg);
    size_t oH  = oXg + (size_t)RCAP * DIN * 2;
    unsigned short* H   = (unsigned short*)(ws + oH);
    size_t oO  = oH + (size_t)RCAP * HDIM * 2;
    unsigned short* O   = (unsigned short*)(ws + oO);
    size_t oW1 = oO + (size_t)RCAP * DOUT * 2;
    unsigned short* W1t = (unsigned short*)(ws + oW1);
    size_t oW2 = oW1 + (size_t)NEXP * HDIM * DIN * 2;
    unsigned short* W2t = (unsigned short*)(ws + oW2);
    // total ~247.6 MB

    init_kernel<<<1, 64, 0, stream>>>(cnt);
    gating_kernel<<<T_TOK, 64, 0, stream>>>(x, noise, gw, gb, nw, nb,
                                            wout, cnt, tok_e, tok_slot, tok_p);
    prefix_kernel<<<1, 1, 0, stream>>>(cnt, poff, t2e, trow);
    gather_kernel<<<2 * T_TOK, 256, 0, stream>>>(x, tok_e, tok_slot, poff, Xg);
    convw_kernel<<<dim3(NEXP, DIN / 64, HDIM / 64), 256, 0, stream>>>(w1, W1t, DIN, HDIM);
    convw_kernel<<<dim3(NEXP, HDIM / 64, DOUT / 64), 256, 0, stream>>>(w2, W2t, HDIM, DOUT);
    gemm_bt_kernel<<<MAXTILE * (HDIM / 128), 256, 0, stream>>>(
        Xg, W1t, H, b1, t2e, trow, DIN, HDIM, 5, 1);
    gemm_bt_kernel<<<MAXTILE * (DOUT / 128), 256, 0, stream>>>(
        H, W2t, O, b2, t2e, trow, HDIM, DOUT, 3, 0);
    combine_kernel<<<T_TOK, 256, 0, stream>>>(O, tok_e, tok_slot, tok_p, poff, xout);
}